// Round 6
// baseline (301.704 us; speedup 1.0000x reference)
//
#include <hip/hip_runtime.h>
#include <hip/hip_bf16.h>

typedef unsigned short u16;
typedef unsigned int u32;
typedef unsigned char u8;
typedef __bf16 bf16x8 __attribute__((ext_vector_type(8)));
typedef float f32x4 __attribute__((ext_vector_type(4)));
typedef float f32x2 __attribute__((ext_vector_type(2)));

#define DIM 256
#define BN_SCALE 0.9999950000374997f // 1/sqrt(1 + 1e-5)

__device__ __forceinline__ float bf2f(u16 u) {
    union { unsigned u; float f; } c; c.u = ((unsigned)u) << 16; return c.f;
}
__device__ __forceinline__ u16 f2bf(float f) {
    union { float f; unsigned u; } c; c.f = f;
    unsigned u = c.u;
    unsigned r = (u + 0x7FFFu + ((u >> 16) & 1u)) >> 16;  // RNE
    return (u16)r;
}
__device__ __forceinline__ float asf(unsigned u) {
    union { unsigned u; float f; } c; c.u = u; return c.f;
}
// 8 bf16 packed in int4 -> 8 f32
__device__ __forceinline__ void cvt8(int4 v, float* f) {
    unsigned a0 = (unsigned)v.x, a1 = (unsigned)v.y, a2 = (unsigned)v.z, a3 = (unsigned)v.w;
    f[0] = asf(a0 << 16); f[1] = asf(a0 & 0xFFFF0000u);
    f[2] = asf(a1 << 16); f[3] = asf(a1 & 0xFFFF0000u);
    f[4] = asf(a2 << 16); f[5] = asf(a2 & 0xFFFF0000u);
    f[6] = asf(a3 << 16); f[7] = asf(a3 & 0xFFFF0000u);
}
// fp8 e4m3 HW converters
__device__ __forceinline__ void dec4(unsigned u, float* f) {
    f32x2 lo = __builtin_amdgcn_cvt_pk_f32_fp8((int)u, false);
    f32x2 hi = __builtin_amdgcn_cvt_pk_f32_fp8((int)u, true);
    f[0] = lo.x; f[1] = lo.y; f[2] = hi.x; f[3] = hi.y;
}
__device__ __forceinline__ unsigned pack4(float a, float b, float c, float d) {
    int u = __builtin_amdgcn_cvt_pk_fp8_f32(a, b, 0, false);
    u = __builtin_amdgcn_cvt_pk_fp8_f32(c, d, u, true);
    return (unsigned)u;
}
// async global->LDS, 16B per lane
__device__ __forceinline__ void gl_lds16(const u16* g, u16* l) {
    __builtin_amdgcn_global_load_lds(
        (__attribute__((address_space(1))) const u32*)(const void*)g,
        (__attribute__((address_space(3))) u32*)(void*)l, 16, 0, 0);
}

// ---------------- dtype detection (1 wave) ----------------
__global__ void k_detect(const u16* __restrict__ xu, const long long* __restrict__ e64,
                         int* __restrict__ flags) {
    int lane = threadIdx.x;
    int plausible = 0;
#pragma unroll
    for (int j = 0; j < 4; ++j) {
        u16 u = xu[lane * 4 + j];
        int ex = (u >> 7) & 0xFF;
        plausible += (u == 0 || (ex >= 115 && ex <= 131)) ? 1 : 0;
    }
#pragma unroll
    for (int o = 32; o; o >>= 1) plausible += __shfl_xor(plausible, o, 64);
    long long hi = e64[lane] >> 32;
    unsigned long long b = __ballot(hi == 0);
    if (lane == 0) {
        flags[0] = (plausible >= 200) ? 1 : 0;
        flags[1] = (b == ~0ULL) ? 1 : 0;
    }
}

// ---------------- batched convert: all float tensors -> bf16 arena ----------------
struct CvtDesc {
    const void* src[15];
    int cum[16];
};
__global__ void k_convert(CvtDesc d, const int* __restrict__ flags,
                          u16* __restrict__ arena, int total) {
    int i = blockIdx.x * 256 + threadIdx.x;
    if (i >= total) return;
    int t = 0;
    while (i >= d.cum[t + 1]) ++t;
    int j = i - d.cum[t];
    u16 v;
    if (flags[0]) v = ((const u16*)d.src[t])[j];
    else          v = f2bf(((const float*)d.src[t])[j]);
    arena[i] = v;
}

// ---------------- transpose 256x256 bf16 matrices ----------------
struct TDesc { const u16* src[12]; u16* dst[12]; };
__global__ __launch_bounds__(256) void k_transpose(TDesc td) {
    __shared__ u16 t[64][72];
    int m = blockIdx.x >> 4, tl = blockIdx.x & 15;
    int tr = (tl >> 2) * 64, tc = (tl & 3) * 64;
    const u16* S = td.src[m];
    u16* D = td.dst[m];
    int r = threadIdx.x >> 2, cs = (threadIdx.x & 3) * 16;
    *(int4*)&t[r][cs]     = *(const int4*)&S[(tr + r) * 256 + tc + cs];
    *(int4*)&t[r][cs + 8] = *(const int4*)&S[(tr + r) * 256 + tc + cs + 8];
    __syncthreads();
    u16 tmp[16];
#pragma unroll
    for (int j = 0; j < 16; ++j) tmp[j] = t[cs + j][r];
    *(int4*)&D[(tc + r) * 256 + tr + cs]     = *(int4*)&tmp[0];
    *(int4*)&D[(tc + r) * 256 + tr + cs + 8] = *(int4*)&tmp[8];
}

// ---------------- edge normalize + degree ----------------
__global__ void k_edges(const int* __restrict__ ei32, const int* __restrict__ flags,
                        int* __restrict__ srcN, int* __restrict__ dstN,
                        int* __restrict__ deg, int E) {
    int e = blockIdx.x * 256 + threadIdx.x;
    if (e >= E) return;
    const long long* ei64 = (const long long*)ei32;
    int w64 = flags[1];
    int s = w64 ? (int)ei64[e]     : ei32[e];
    int d = w64 ? (int)ei64[E + e] : ei32[E + e];
    srcN[e] = s; dstN[e] = d;
    atomicAdd(&deg[d], 1);
}

__global__ __launch_bounds__(1024) void k_scan(const int* __restrict__ deg,
                                               int* __restrict__ offs,
                                               int* __restrict__ cursor, int N, int E) {
    __shared__ int s[1024];
    int t = threadIdx.x;
    int P = (N + 1023) >> 10;
    int base = t * P;
    int run = 0;
    for (int j = 0; j < P; ++j) { int idx = base + j; if (idx < N) run += deg[idx]; }
    s[t] = run;
    __syncthreads();
    int total = run;
    for (int off = 1; off < 1024; off <<= 1) {
        int v = 0;
        if (t >= off) v = s[t - off];
        __syncthreads();
        if (t >= off) s[t] += v;
        __syncthreads();
    }
    int r = s[t] - total;
    for (int j = 0; j < P; ++j) {
        int idx = base + j;
        if (idx < N) { offs[idx] = r; cursor[idx] = r; r += deg[idx]; }
    }
    if (t == 0) offs[N] = E;
}

__global__ void k_fill(const int* __restrict__ srcN, const int* __restrict__ dstN,
                       int* __restrict__ cursor, int* __restrict__ csr, int E) {
    int e = blockIdx.x * 256 + threadIdx.x;
    if (e < E) {
        int d = dstN[e];
        int pos = atomicAdd(&cursor[d], 1);
        csr[pos] = srcN[e];
    }
}

// ---------------- fused QKVS GEMM: out[M x 1024] = x @ WT^T + bias; k8/v8 fp8 side-pack ----------------
__global__ __launch_bounds__(256) void gemm_qkvs(
    const u16* __restrict__ x, const u16* __restrict__ WT,
    const u16* __restrict__ bias, u16* __restrict__ out,
    u8* __restrict__ k8, u8* __restrict__ v8, int M) {
    __shared__ __align__(16) u16 lds[16384];
    u16* As = lds;
    u16* Bs = lds + 8192;
    int tid = threadIdx.x, w = tid >> 6, lane = tid & 63;
    int l15 = lane & 15, quad = lane >> 4;
    int lr = lane >> 3, lc = lane & 7;
    int bm0 = blockIdx.x * 128, bn0 = blockIdx.y * 128;
    f32x4 acc[4][4];
#pragma unroll
    for (int a = 0; a < 4; ++a)
#pragma unroll
        for (int b = 0; b < 4; ++b) acc[a][b] = (f32x4){0.f, 0.f, 0.f, 0.f};

    for (int k0 = 0; k0 < 256; k0 += 64) {
#pragma unroll
        for (int j = 0; j < 4; ++j) {
            int ar = (w * 4 + j) * 8 + lr;
            int grow = bm0 + ar; if (grow >= M) grow = M - 1;
            gl_lds16(x + (size_t)grow * 256 + k0 + lc * 8, &As[(w * 4 + j) * 512]);
        }
#pragma unroll
        for (int j = 0; j < 4; ++j) {
            int nr = (w * 4 + j) * 8 + lr;
            gl_lds16(WT + (size_t)(bn0 + nr) * 256 + k0 + lc * 8, &Bs[(w * 4 + j) * 512]);
        }
        __syncthreads();
        int wm = w & 1, wn = w >> 1;
#pragma unroll
        for (int s = 0; s < 2; ++s) {
            bf16x8 a[4], b[4];
#pragma unroll
            for (int t = 0; t < 4; ++t)
                a[t] = *(const bf16x8*)&As[(wm * 64 + t * 16 + l15) * 64 + s * 32 + quad * 8];
#pragma unroll
            for (int t = 0; t < 4; ++t)
                b[t] = *(const bf16x8*)&Bs[(wn * 64 + t * 16 + l15) * 64 + s * 32 + quad * 8];
#pragma unroll
            for (int rt = 0; rt < 4; ++rt)
#pragma unroll
                for (int ct = 0; ct < 4; ++ct)
                    acc[rt][ct] = __builtin_amdgcn_mfma_f32_16x16x32_bf16(a[rt], b[ct], acc[rt][ct], 0, 0, 0);
        }
        __syncthreads();
    }
    int wm = w & 1, wn = w >> 1;
    u16* oL = lds + w * 4096;
#pragma unroll
    for (int rt = 0; rt < 4; ++rt)
#pragma unroll
        for (int ct = 0; ct < 4; ++ct) {
            int col = bn0 + wn * 64 + ct * 16 + l15;
            float bv = bf2f(bias[col]);
#pragma unroll
            for (int r = 0; r < 4; ++r)
                oL[(rt * 16 + quad * 4 + r) * 64 + ct * 16 + l15] = f2bf(acc[rt][ct][r] + bv);
        }
    __syncthreads();
    int c0 = bn0 + wn * 64 + lc * 8;   // this lane's 8-col segment
#pragma unroll
    for (int j = 0; j < 8; ++j) {
        int orow = j * 8 + lr;
        int grow = bm0 + wm * 64 + orow;
        if (grow < M) {
            int4 hv = *(const int4*)&oL[orow * 64 + lc * 8];
            *(int4*)&out[(size_t)grow * 1024 + c0] = hv;
            if (c0 >= 256 && c0 < 768) {     // K or V: side-pack to fp8
                float f[8]; cvt8(hv, f);
                uint2 o8;
                o8.x = pack4(f[0], f[1], f[2], f[3]);
                o8.y = pack4(f[4], f[5], f[6], f[7]);
                u8* dst = (c0 < 512) ? (k8 + (size_t)grow * 256 + (c0 - 256))
                                     : (v8 + (size_t)grow * 256 + (c0 - 512));
                *(uint2*)dst = o8;
            }
        }
    }
}

// ---------------- attention pass 1: logits + per-node (max, 1/denom); K-only gathers ----------------
__global__ __launch_bounds__(256) void k_attn1(const u16* __restrict__ qkvs,
                                               const u8* __restrict__ k8,
                                               const int* __restrict__ csr,
                                               const int* __restrict__ offs,
                                               float* __restrict__ le,
                                               float2* __restrict__ md, int N) {
    int wv = threadIdx.x >> 6, lane = threadIdx.x & 63;
    int i = blockIdx.x * 4 + wv;
    if (i >= N) return;
    int sub = lane & 7, e8 = lane >> 3;

    float qf[32];
    {
        const u16* qp = qkvs + (size_t)i * 1024 + sub * 32;
#pragma unroll
        for (int j = 0; j < 4; ++j) {
            int4 v = *(const int4*)(qp + j * 8);
            float t[8]; cvt8(v, t);
#pragma unroll
            for (int d = 0; d < 8; ++d) qf[j * 8 + d] = t[d] * 0.0625f;
        }
    }
    int e0 = offs[i], e1 = offs[i + 1];
    float m = -1e30f, denom = 0.f;
    for (int base = e0; base < e1; base += 8) {
        int e = base + e8;
        int sidx = csr[(e < e1) ? e : (e1 - 1)];
        const u8* kp = k8 + (size_t)sidx * 256 + sub * 32;
        uint4 ka = *(const uint4*)kp;
        uint4 kb = *(const uint4*)(kp + 16);
        unsigned kw[8] = {ka.x, ka.y, ka.z, ka.w, kb.x, kb.y, kb.z, kb.w};
        float p = 0.f;
#pragma unroll
        for (int j = 0; j < 8; ++j) {
            float t[4]; dec4(kw[j], t);
            p += qf[j * 4] * t[0] + qf[j * 4 + 1] * t[1] + qf[j * 4 + 2] * t[2] + qf[j * 4 + 3] * t[3];
        }
        p += __shfl_xor(p, 1, 64);
        p += __shfl_xor(p, 2, 64);
        p += __shfl_xor(p, 4, 64);
        if (e >= e1) p = -1e30f;
        if (sub == 0 && e < e1) le[e] = p;
        float pm = p;
        pm = fmaxf(pm, __shfl_xor(pm, 8, 64));
        pm = fmaxf(pm, __shfl_xor(pm, 16, 64));
        pm = fmaxf(pm, __shfl_xor(pm, 32, 64));
        if (pm > m) {
            denom *= __expf(m - pm);
            m = pm;
        }
        denom += __expf(p - m);
    }
    denom += __shfl_xor(denom, 8, 64);
    denom += __shfl_xor(denom, 16, 64);
    denom += __shfl_xor(denom, 32, 64);
    if (lane == 0) {
        float2 o; o.x = m; o.y = (denom > 0.f) ? 1.f / denom : 0.f;
        md[i] = o;
    }
}

// ---------------- attention pass 2: weighted V-agg + skip + relu; V-only gathers ----------------
__global__ __launch_bounds__(256) void k_attn2(const u16* __restrict__ qkvs,
                                               const u8* __restrict__ v8,
                                               const int* __restrict__ csr,
                                               const int* __restrict__ offs,
                                               const float* __restrict__ le,
                                               const float2* __restrict__ md,
                                               u16* __restrict__ hb,
                                               u8* __restrict__ h8, int N) {
    int wv = threadIdx.x >> 6, lane = threadIdx.x & 63;
    int i = blockIdx.x * 4 + wv;
    if (i >= N) return;
    int sub = lane & 7, e8 = lane >> 3;
    float2 c = md[i];
    float m = c.x, invd = c.y;
    int e0 = offs[i], e1 = offs[i + 1];
    float acc[32];
#pragma unroll
    for (int j = 0; j < 32; ++j) acc[j] = 0.f;

    for (int base = e0; base < e1; base += 8) {
        int e = base + e8;
        int eg = (e < e1) ? e : (e1 - 1);
        int sidx = csr[eg];
        float l = (e < e1) ? le[eg] : -1e30f;
        const u8* vp = v8 + (size_t)sidx * 256 + sub * 32;
        uint4 va = *(const uint4*)vp;
        uint4 vb = *(const uint4*)(vp + 16);
        float w = __expf(l - m) * invd;
        unsigned vw[8] = {va.x, va.y, va.z, va.w, vb.x, vb.y, vb.z, vb.w};
#pragma unroll
        for (int j = 0; j < 8; ++j) {
            float t[4]; dec4(vw[j], t);
            acc[j * 4]     += w * t[0];
            acc[j * 4 + 1] += w * t[1];
            acc[j * 4 + 2] += w * t[2];
            acc[j * 4 + 3] += w * t[3];
        }
    }
#pragma unroll
    for (int j = 0; j < 32; ++j) {
        acc[j] += __shfl_xor(acc[j], 8, 64);
        acc[j] += __shfl_xor(acc[j], 16, 64);
        acc[j] += __shfl_xor(acc[j], 32, 64);
    }
    if (e8 == 0) {
        const u16* skp = qkvs + (size_t)i * 1024 + 768 + sub * 32;
        float h[32];
#pragma unroll
        for (int j = 0; j < 4; ++j) {
            int4 sv = *(const int4*)(skp + j * 8);
            float t[8]; cvt8(sv, t);
            u16 o[8];
#pragma unroll
            for (int d = 0; d < 8; ++d) {
                float hv = fmaxf(acc[j * 8 + d] + t[d], 0.f);
                h[j * 8 + d] = hv;
                o[d] = f2bf(hv);
            }
            *(int4*)(hb + (size_t)i * 256 + sub * 32 + j * 8) = *(const int4*)o;
        }
        uint4 p0, p1;
        p0.x = pack4(h[0], h[1], h[2], h[3]);   p0.y = pack4(h[4], h[5], h[6], h[7]);
        p0.z = pack4(h[8], h[9], h[10], h[11]); p0.w = pack4(h[12], h[13], h[14], h[15]);
        p1.x = pack4(h[16], h[17], h[18], h[19]); p1.y = pack4(h[20], h[21], h[22], h[23]);
        p1.z = pack4(h[24], h[25], h[26], h[27]); p1.w = pack4(h[28], h[29], h[30], h[31]);
        *(uint4*)(h8 + (size_t)i * 256 + sub * 32) = p0;
        *(uint4*)(h8 + (size_t)i * 256 + sub * 32 + 16) = p1;
    }
}

// ---------------- SAGE mean aggregation over fp8 h ----------------
__global__ __launch_bounds__(256) void k_agg(const u8* __restrict__ h8,
                                             const int* __restrict__ csr,
                                             const int* __restrict__ offs,
                                             u16* __restrict__ mean_out, int N) {
    int half = threadIdx.x >> 5, hl = threadIdx.x & 31;
    int i = blockIdx.x * 8 + half;
    if (i >= N) return;
    int e0 = offs[i], e1 = offs[i + 1];
    const u8* base = h8 + (unsigned)hl * 8;
    float acc[8];
#pragma unroll
    for (int d = 0; d < 8; ++d) acc[d] = 0.f;
    int e = e0;
    for (; e + 8 <= e1; e += 8) {
        uint2 r[8];
#pragma unroll
        for (int j = 0; j < 8; ++j)
            r[j] = *(const uint2*)(base + (size_t)csr[e + j] * 256);
#pragma unroll
        for (int j = 0; j < 8; ++j) {
            float f0[4], f1[4];
            dec4(r[j].x, f0); dec4(r[j].y, f1);
            acc[0] += f0[0]; acc[1] += f0[1]; acc[2] += f0[2]; acc[3] += f0[3];
            acc[4] += f1[0]; acc[5] += f1[1]; acc[6] += f1[2]; acc[7] += f1[3];
        }
    }
    for (; e < e1; ++e) {
        uint2 r0 = *(const uint2*)(base + (size_t)csr[e] * 256);
        float f0[4], f1[4];
        dec4(r0.x, f0); dec4(r0.y, f1);
        acc[0] += f0[0]; acc[1] += f0[1]; acc[2] += f0[2]; acc[3] += f0[3];
        acc[4] += f1[0]; acc[5] += f1[1]; acc[6] += f1[2]; acc[7] += f1[3];
    }
    int dg = e1 - e0; if (dg < 1) dg = 1;
    float inv = 1.f / (float)dg;
    u16 o16[8];
#pragma unroll
    for (int d = 0; d < 8; ++d) o16[d] = f2bf(acc[d] * inv);
    *(int4*)(mean_out + (size_t)i * 256 + (unsigned)hl * 8) = *(const int4*)o16;
}

// ---------------- SAGE GEMM (K=512 concat) + fused BN / gated residual / relu ----------------
__global__ __launch_bounds__(256) void gemm_sage(
    const u16* __restrict__ meanA, const u16* __restrict__ hin,
    const u16* __restrict__ WlT, const u16* __restrict__ WrT,
    const u16* __restrict__ bl, const u16* __restrict__ gamma,
    const u16* __restrict__ beta, const u16* __restrict__ alpha,
    u16* __restrict__ hout, u8* __restrict__ h8out, float* __restrict__ fout, int M) {
    __shared__ __align__(16) u16 lds[12288];
    u16* As = lds;
    u16* Bs = lds + 8192;
    int tid = threadIdx.x, w = tid >> 6, lane = tid & 63;
    int l15 = lane & 15, quad = lane >> 4;
    int lr = lane >> 3, lc = lane & 7;
    int bm0 = blockIdx.x * 128, n0 = blockIdx.y * 64;
    f32x4 acc[2][4];
#pragma unroll
    for (int a = 0; a < 2; ++a)
#pragma unroll
        for (int b = 0; b < 4; ++b) acc[a][b] = (f32x4){0.f, 0.f, 0.f, 0.f};

    for (int k0 = 0; k0 < 512; k0 += 64) {
        const u16* Asrc = (k0 < 256) ? meanA : hin;
        const u16* Bsrc = (k0 < 256) ? WlT : WrT;
        int kc = k0 & 255;
#pragma unroll
        for (int j = 0; j < 4; ++j) {
            int ar = (w * 4 + j) * 8 + lr;
            int grow = bm0 + ar; if (grow >= M) grow = M - 1;
            gl_lds16(Asrc + (size_t)grow * 256 + kc + lc * 8, &As[(w * 4 + j) * 512]);
        }
#pragma unroll
        for (int j = 0; j < 2; ++j) {
            int nr = (w * 2 + j) * 8 + lr;
            gl_lds16(Bsrc + (size_t)(n0 + nr) * 256 + kc + lc * 8, &Bs[(w * 2 + j) * 512]);
        }
        __syncthreads();
#pragma unroll
        for (int s = 0; s < 2; ++s) {
            bf16x8 a[2], b[4];
#pragma unroll
            for (int t = 0; t < 2; ++t)
                a[t] = *(const bf16x8*)&As[(w * 32 + t * 16 + l15) * 64 + s * 32 + quad * 8];
#pragma unroll
            for (int t = 0; t < 4; ++t)
                b[t] = *(const bf16x8*)&Bs[(t * 16 + l15) * 64 + s * 32 + quad * 8];
#pragma unroll
            for (int rt = 0; rt < 2; ++rt)
#pragma unroll
                for (int ct = 0; ct < 4; ++ct)
                    acc[rt][ct] = __builtin_amdgcn_mfma_f32_16x16x32_bf16(a[rt], b[ct], acc[rt][ct], 0, 0, 0);
        }
        __syncthreads();
    }

    float al = 1.f / (1.f + __expf(-bf2f(alpha[0])));
    float alc = 1.f - al;
    u16* oL = lds + w * 2048;
#pragma unroll
    for (int rt = 0; rt < 2; ++rt)
#pragma unroll
        for (int ct = 0; ct < 4; ++ct) {
            int col = n0 + ct * 16 + l15;
            float g  = bf2f(gamma[col]) * BN_SCALE;
            float be = bf2f(beta[col]);
            float bb = bf2f(bl[col]);
#pragma unroll
            for (int r = 0; r < 4; ++r) {
                int grow = bm0 + w * 32 + rt * 16 + quad * 4 + r;
                float z = (acc[rt][ct][r] + bb) * g + be;
                float prev = (grow < M) ? bf2f(hin[(size_t)grow * 256 + col]) : 0.f;
                z = al * z + alc * prev;
                z = fmaxf(z, 0.f);
                oL[(rt * 16 + quad * 4 + r) * 64 + ct * 16 + l15] = f2bf(z);
                if (fout && grow < M) fout[(size_t)grow * 256 + col] = z;
            }
        }
    __syncthreads();
#pragma unroll
    for (int j = 0; j < 4; ++j) {
        int orow = j * 8 + lr;
        int grow = bm0 + w * 32 + orow;
        if (grow < M) {
            int4 hv = *(const int4*)&oL[orow * 64 + lc * 8];
            *(int4*)&hout[(size_t)grow * 256 + n0 + lc * 8] = hv;
            float f[8]; cvt8(hv, f);
            uint2 o8;
            o8.x = pack4(f[0], f[1], f[2], f[3]);
            o8.y = pack4(f[4], f[5], f[6], f[7]);
            *(uint2*)(h8out + (size_t)grow * 256 + n0 + lc * 8) = o8;
        }
    }
}

extern "C" void kernel_launch(void* const* d_in, const int* in_sizes, int n_in,
                              void* d_out, int out_size, void* d_ws, size_t ws_size,
                              hipStream_t stream) {
    int N = in_sizes[0] / DIM;
    int E = in_sizes[1] / 2;
    int L = in_sizes[10] / (DIM * DIM);

    const int map[15] = {0, 2, 4, 6, 8, 10, 12, 3, 5, 7, 9, 11, 13, 14, 15};
    CvtDesc cd;
    cd.cum[0] = 0;
    for (int t = 0; t < 15; ++t) {
        cd.src[t] = d_in[map[t]];
        cd.cum[t + 1] = cd.cum[t] + in_sizes[map[t]];
    }
    int total = cd.cum[15];

    char* ws = (char*)d_ws;
    size_t off = 0;
    auto take = [&](size_t bytes) { size_t c = off; off = (off + bytes + 255) & ~255ULL; return c; };

    int* flags  = (int*)(ws + take(16));
    u16* arena  = (u16*)(ws + take((size_t)total * 2));
    u16* WT     = (u16*)(ws + take((size_t)(4 + 2 * L) * DIM * DIM * 2));
    int* srcN   = (int*)(ws + take((size_t)E * 4));       // dead after k_fill -> h8 overlay
    int* dstN   = (int*)(ws + take((size_t)E * 4));
    int* csr    = (int*)(ws + take((size_t)E * 4));
    int* deg    = (int*)(ws + take((size_t)N * 4));
    int* offs   = (int*)(ws + take((size_t)(N + 1) * 4));
    int* cursor = (int*)(ws + take((size_t)N * 4));
    u16* hB0    = (u16*)(ws + take((size_t)N * DIM * 2));
    u8*  k8     = (u8*)(ws + take((size_t)N * 256));
    u8*  v8     = (u8*)(ws + take((size_t)N * 256));
    float* le   = (float*)(ws + take((size_t)E * 4));
    float2* md  = (float2*)(ws + take((size_t)N * 8));
    u16* qkvsB  = (u16*)(ws + take((size_t)N * 1024 * 2)); // dead after k_attn2
    u16* meanB  = qkvsB;                                   // overlay
    u16* hB1    = qkvsB + (size_t)N * DIM;                 // overlay
    u8*  h8     = (u8*)srcN;                               // overlay: N*256 B == srcN+dstN (2*E*4)
    (void)ws_size; (void)n_in; (void)out_size;

    const u16* xb  = arena + cd.cum[0];
    const u16* Wqb = arena + cd.cum[1];
    const u16* Wkb = arena + cd.cum[2];
    const u16* Wvb = arena + cd.cum[3];
    const u16* Wsb = arena + cd.cum[4];
    const u16* Wlb = arena + cd.cum[5];
    const u16* Wrb = arena + cd.cum[6];
    const u16* biasF = arena + cd.cum[7];
    const u16* blb = arena + cd.cum[11];
    const u16* gmb = arena + cd.cum[12];
    const u16* btb = arena + cd.cum[13];
    const u16* alb = arena + cd.cum[14];

    k_detect<<<1, 64, 0, stream>>>((const u16*)d_in[0], (const long long*)d_in[1], flags);
    k_convert<<<(total + 255) / 256, 256, 0, stream>>>(cd, flags, arena, total);

    TDesc td;
    int nMat = 0;
    const u16* wsrc[4] = {Wqb, Wkb, Wvb, Wsb};
    for (int t = 0; t < 4; ++t) { td.src[nMat] = wsrc[t]; td.dst[nMat] = WT + (size_t)nMat * DIM * DIM; ++nMat; }
    for (int l = 0; l < L; ++l) { td.src[nMat] = Wlb + (size_t)l * DIM * DIM; td.dst[nMat] = WT + (size_t)nMat * DIM * DIM; ++nMat; }
    for (int l = 0; l < L; ++l) { td.src[nMat] = Wrb + (size_t)l * DIM * DIM; td.dst[nMat] = WT + (size_t)nMat * DIM * DIM; ++nMat; }
    k_transpose<<<nMat * 16, 256, 0, stream>>>(td);

    hipMemsetAsync(deg, 0, (size_t)N * 4, stream);
    int eb = (E + 255) / 256;
    k_edges<<<eb, 256, 0, stream>>>((const int*)d_in[1], flags, srcN, dstN, deg, E);
    k_scan<<<1, 1024, 0, stream>>>(deg, offs, cursor, N, E);
    k_fill<<<eb, 256, 0, stream>>>(srcN, dstN, cursor, csr, E);

    int Mb128 = (N + 127) / 128;
    gemm_qkvs<<<dim3(Mb128, 8), 256, 0, stream>>>(xb, WT, biasF, qkvsB, k8, v8, N);
    k_attn1<<<(N + 3) / 4, 256, 0, stream>>>(qkvsB, k8, csr, offs, le, md, N);
    k_attn2<<<(N + 3) / 4, 256, 0, stream>>>(qkvsB, v8, csr, offs, le, md, hB0, h8, N);

    for (int l = 0; l < L; ++l) {
        const u16* hin = (l & 1) ? hB1 : hB0;
        u16* hout      = (l & 1) ? hB0 : hB1;
        float* fout = (l == L - 1) ? (float*)d_out : nullptr;
        k_agg<<<(N + 7) / 8, 256, 0, stream>>>(h8, csr, offs, meanB, N);
        gemm_sage<<<dim3(Mb128, 4), 256, 0, stream>>>(
            meanB, hin, WT + (size_t)(4 + l) * DIM * DIM, WT + (size_t)(4 + L + l) * DIM * DIM,
            blb + (size_t)l * DIM, gmb + (size_t)l * DIM, btb + (size_t)l * DIM,
            alb, hout, h8, fout, N);
    }
}

// Round 7
// 293.087 us; speedup vs baseline: 1.0294x; 1.0294x over previous
//
#include <hip/hip_runtime.h>
#include <hip/hip_bf16.h>

typedef unsigned short u16;
typedef unsigned int u32;
typedef unsigned char u8;
typedef __bf16 bf16x8 __attribute__((ext_vector_type(8)));
typedef float f32x4 __attribute__((ext_vector_type(4)));
typedef float f32x2 __attribute__((ext_vector_type(2)));

#define DIM 256
#define BN_SCALE 0.9999950000374997f // 1/sqrt(1 + 1e-5)

__device__ __forceinline__ float bf2f(u16 u) {
    union { unsigned u; float f; } c; c.u = ((unsigned)u) << 16; return c.f;
}
__device__ __forceinline__ u16 f2bf(float f) {
    union { float f; unsigned u; } c; c.f = f;
    unsigned u = c.u;
    unsigned r = (u + 0x7FFFu + ((u >> 16) & 1u)) >> 16;  // RNE
    return (u16)r;
}
__device__ __forceinline__ float asf(unsigned u) {
    union { unsigned u; float f; } c; c.u = u; return c.f;
}
__device__ __forceinline__ void cvt8(int4 v, float* f) {
    unsigned a0 = (unsigned)v.x, a1 = (unsigned)v.y, a2 = (unsigned)v.z, a3 = (unsigned)v.w;
    f[0] = asf(a0 << 16); f[1] = asf(a0 & 0xFFFF0000u);
    f[2] = asf(a1 << 16); f[3] = asf(a1 & 0xFFFF0000u);
    f[4] = asf(a2 << 16); f[5] = asf(a2 & 0xFFFF0000u);
    f[6] = asf(a3 << 16); f[7] = asf(a3 & 0xFFFF0000u);
}
__device__ __forceinline__ void dec4(unsigned u, float* f) {
    f32x2 lo = __builtin_amdgcn_cvt_pk_f32_fp8((int)u, false);
    f32x2 hi = __builtin_amdgcn_cvt_pk_f32_fp8((int)u, true);
    f[0] = lo.x; f[1] = lo.y; f[2] = hi.x; f[3] = hi.y;
}
__device__ __forceinline__ unsigned pack4(float a, float b, float c, float d) {
    int u = __builtin_amdgcn_cvt_pk_fp8_f32(a, b, 0, false);
    u = __builtin_amdgcn_cvt_pk_fp8_f32(c, d, u, true);
    return (unsigned)u;
}
__device__ __forceinline__ void gl_lds16(const u16* g, u16* l) {
    __builtin_amdgcn_global_load_lds(
        (__attribute__((address_space(1))) const u32*)(const void*)g,
        (__attribute__((address_space(3))) u32*)(void*)l, 16, 0, 0);
}

// wave-uniform dtype detect: .x = floats-are-bf16, .y = edges-are-int64
__device__ __forceinline__ int2 detect_inline(const u16* __restrict__ xu,
                                              const long long* __restrict__ e64) {
    int lane = threadIdx.x & 63;
    int pl = 0;
#pragma unroll
    for (int j = 0; j < 4; ++j) {
        u16 u = xu[lane * 4 + j];
        int ex = (u >> 7) & 0xFF;
        pl += (u == 0 || (ex >= 115 && ex <= 131)) ? 1 : 0;
    }
#pragma unroll
    for (int o = 32; o; o >>= 1) pl += __shfl_xor(pl, o, 64);
    long long hi = e64[lane] >> 32;
    unsigned long long b = __ballot(hi == 0);
    int2 r; r.x = (pl >= 200) ? 1 : 0; r.y = (b == ~0ULL) ? 1 : 0;
    return r;
}

// ---------------- convert x + vectors -> bf16 arena; zero deg ----------------
struct CvtDesc { const void* src[9]; int cum[10]; };
__global__ void k_convert(CvtDesc d, const u16* __restrict__ xu,
                          const long long* __restrict__ e64,
                          u16* __restrict__ arena, int total,
                          int* __restrict__ deg, int N) {
    int2 fl = detect_inline(xu, e64);
    int i = blockIdx.x * 256 + threadIdx.x;
    if (i < N) deg[i] = 0;
    if (i >= total) return;
    int t = 0;
    while (i >= d.cum[t + 1]) ++t;
    int j = i - d.cum[t];
    u16 v;
    if (fl.x) v = ((const u16*)d.src[t])[j];
    else      v = f2bf(((const float*)d.src[t])[j]);
    arena[i] = v;
}

// ---------------- transpose weights from ORIGINAL tensors (f32 or bf16) ----------------
// mats: 0..3 = Wq,Wk,Wv,Ws (own base, layer 0); 4..3+L = Wl (base d_in[10], layer (m-4));
// 4+L..3+2L = Wr (base d_in[12], layer (m-4-L)).
struct TDesc { const void* base[3]; int L; };
__global__ __launch_bounds__(256) void k_transpose(TDesc td, const void* w0,
                                                   const void* w1, const void* w2,
                                                   const void* w3,
                                                   const u16* __restrict__ xu,
                                                   const long long* __restrict__ e64,
                                                   u16* __restrict__ WT) {
    __shared__ u16 t[64][72];
    int2 fl = detect_inline(xu, e64);
    int m = blockIdx.x >> 4, tl = blockIdx.x & 15;
    int tr = (tl >> 2) * 64, tc = (tl & 3) * 64;
    const void* S;
    size_t eoff = 0;
    if (m < 4)            S = (m == 0) ? w0 : (m == 1) ? w1 : (m == 2) ? w2 : w3;
    else if (m < 4 + td.L) { S = td.base[1]; eoff = (size_t)(m - 4) * DIM * DIM; }
    else                   { S = td.base[2]; eoff = (size_t)(m - 4 - td.L) * DIM * DIM; }
    u16* D = WT + (size_t)m * DIM * DIM;
    int r = threadIdx.x >> 2, cs = (threadIdx.x & 3) * 16;
    size_t src_idx = eoff + (size_t)(tr + r) * 256 + tc + cs;
    if (fl.x) {
        const u16* S16 = (const u16*)S + src_idx;
        *(int4*)&t[r][cs]     = *(const int4*)S16;
        *(int4*)&t[r][cs + 8] = *(const int4*)(S16 + 8);
    } else {
        const float* SF = (const float*)S + src_idx;
        u16 tmp[16];
#pragma unroll
        for (int q = 0; q < 4; ++q) {
            float4 v = *(const float4*)(SF + q * 4);
            tmp[q * 4] = f2bf(v.x); tmp[q * 4 + 1] = f2bf(v.y);
            tmp[q * 4 + 2] = f2bf(v.z); tmp[q * 4 + 3] = f2bf(v.w);
        }
        *(int4*)&t[r][cs]     = *(const int4*)&tmp[0];
        *(int4*)&t[r][cs + 8] = *(const int4*)&tmp[8];
    }
    __syncthreads();
    u16 tmp[16];
#pragma unroll
    for (int j = 0; j < 16; ++j) tmp[j] = t[cs + j][r];
    *(int4*)&D[(tc + r) * 256 + tr + cs]     = *(int4*)&tmp[0];
    *(int4*)&D[(tc + r) * 256 + tr + cs + 8] = *(int4*)&tmp[8];
}

// ---------------- degree histogram / CSR fill from ORIGINAL edges ----------------
__global__ void k_edges(const int* __restrict__ ei32, const u16* __restrict__ xu,
                        int* __restrict__ deg, int E) {
    int2 fl = detect_inline(xu, (const long long*)ei32);
    int e = blockIdx.x * 256 + threadIdx.x;
    if (e >= E) return;
    const long long* ei64 = (const long long*)ei32;
    int d = fl.y ? (int)ei64[E + e] : ei32[E + e];
    atomicAdd(&deg[d], 1);
}

__global__ __launch_bounds__(1024) void k_scan(const int* __restrict__ deg,
                                               int* __restrict__ offs,
                                               int* __restrict__ cursor, int N, int E) {
    __shared__ int s[1024];
    int t = threadIdx.x;
    int P = (N + 1023) >> 10;
    int base = t * P;
    int run = 0;
    for (int j = 0; j < P; ++j) { int idx = base + j; if (idx < N) run += deg[idx]; }
    s[t] = run;
    __syncthreads();
    int total = run;
    for (int off = 1; off < 1024; off <<= 1) {
        int v = 0;
        if (t >= off) v = s[t - off];
        __syncthreads();
        if (t >= off) s[t] += v;
        __syncthreads();
    }
    int r = s[t] - total;
    for (int j = 0; j < P; ++j) {
        int idx = base + j;
        if (idx < N) { offs[idx] = r; cursor[idx] = r; r += deg[idx]; }
    }
    if (t == 0) offs[N] = E;
}

__global__ void k_fill(const int* __restrict__ ei32, const u16* __restrict__ xu,
                       int* __restrict__ cursor, int* __restrict__ csr, int E) {
    int2 fl = detect_inline(xu, (const long long*)ei32);
    int e = blockIdx.x * 256 + threadIdx.x;
    if (e >= E) return;
    const long long* ei64 = (const long long*)ei32;
    int s = fl.y ? (int)ei64[e]     : ei32[e];
    int d = fl.y ? (int)ei64[E + e] : ei32[E + e];
    int pos = atomicAdd(&cursor[d], 1);
    csr[pos] = s;
}

// ---------------- fused QKVS GEMM + kv8 fp8 side-pack ----------------
__global__ __launch_bounds__(256) void gemm_qkvs(
    const u16* __restrict__ x, const u16* __restrict__ WT,
    const u16* __restrict__ bias, u16* __restrict__ out,
    u8* __restrict__ kv8, int M) {
    __shared__ __align__(16) u16 lds[16384];
    u16* As = lds;
    u16* Bs = lds + 8192;
    int tid = threadIdx.x, w = tid >> 6, lane = tid & 63;
    int l15 = lane & 15, quad = lane >> 4;
    int lr = lane >> 3, lc = lane & 7;
    int bm0 = blockIdx.x * 128, bn0 = blockIdx.y * 128;
    f32x4 acc[4][4];
#pragma unroll
    for (int a = 0; a < 4; ++a)
#pragma unroll
        for (int b = 0; b < 4; ++b) acc[a][b] = (f32x4){0.f, 0.f, 0.f, 0.f};

    for (int k0 = 0; k0 < 256; k0 += 64) {
#pragma unroll
        for (int j = 0; j < 4; ++j) {
            int ar = (w * 4 + j) * 8 + lr;
            int grow = bm0 + ar; if (grow >= M) grow = M - 1;
            gl_lds16(x + (size_t)grow * 256 + k0 + lc * 8, &As[(w * 4 + j) * 512]);
        }
#pragma unroll
        for (int j = 0; j < 4; ++j) {
            int nr = (w * 4 + j) * 8 + lr;
            gl_lds16(WT + (size_t)(bn0 + nr) * 256 + k0 + lc * 8, &Bs[(w * 4 + j) * 512]);
        }
        __syncthreads();
        int wm = w & 1, wn = w >> 1;
#pragma unroll
        for (int s = 0; s < 2; ++s) {
            bf16x8 a[4], b[4];
#pragma unroll
            for (int t = 0; t < 4; ++t)
                a[t] = *(const bf16x8*)&As[(wm * 64 + t * 16 + l15) * 64 + s * 32 + quad * 8];
#pragma unroll
            for (int t = 0; t < 4; ++t)
                b[t] = *(const bf16x8*)&Bs[(wn * 64 + t * 16 + l15) * 64 + s * 32 + quad * 8];
#pragma unroll
            for (int rt = 0; rt < 4; ++rt)
#pragma unroll
                for (int ct = 0; ct < 4; ++ct)
                    acc[rt][ct] = __builtin_amdgcn_mfma_f32_16x16x32_bf16(a[rt], b[ct], acc[rt][ct], 0, 0, 0);
        }
        __syncthreads();
    }
    int wm = w & 1, wn = w >> 1;
    u16* oL = lds + w * 4096;
#pragma unroll
    for (int rt = 0; rt < 4; ++rt)
#pragma unroll
        for (int ct = 0; ct < 4; ++ct) {
            int col = bn0 + wn * 64 + ct * 16 + l15;
            float bv = bf2f(bias[col]);
#pragma unroll
            for (int r = 0; r < 4; ++r)
                oL[(rt * 16 + quad * 4 + r) * 64 + ct * 16 + l15] = f2bf(acc[rt][ct][r] + bv);
        }
    __syncthreads();
    int c0 = bn0 + wn * 64 + lc * 8;
#pragma unroll
    for (int j = 0; j < 8; ++j) {
        int orow = j * 8 + lr;
        int grow = bm0 + wm * 64 + orow;
        if (grow < M) {
            int4 hv = *(const int4*)&oL[orow * 64 + lc * 8];
            *(int4*)&out[(size_t)grow * 1024 + c0] = hv;
            if (c0 >= 256 && c0 < 768) {
                float f[8]; cvt8(hv, f);
                uint2 o8;
                o8.x = pack4(f[0], f[1], f[2], f[3]);
                o8.y = pack4(f[4], f[5], f[6], f[7]);
                *(uint2*)(kv8 + (size_t)grow * 512 + (c0 - 256)) = o8;
            }
        }
    }
}

// ---------------- fused attention: single pass, fp8 K+V, online softmax ----------------
__global__ __launch_bounds__(256) void k_attn(const u16* __restrict__ qkvs,
                                              const u8* __restrict__ kv8,
                                              const int* __restrict__ csr,
                                              const int* __restrict__ offs,
                                              u16* __restrict__ hb,
                                              u8* __restrict__ h8, int N) {
    int wv = threadIdx.x >> 6, lane = threadIdx.x & 63;
    int i = blockIdx.x * 4 + wv;
    if (i >= N) return;
    int sub = lane & 7, e8 = lane >> 3;
    size_t row = (size_t)i * 1024;

    float qf[32];
    {
        const u16* qp = qkvs + row + sub * 32;
#pragma unroll
        for (int j = 0; j < 4; ++j) {
            int4 v = *(const int4*)(qp + j * 8);
            float t[8]; cvt8(v, t);
#pragma unroll
            for (int d = 0; d < 8; ++d) qf[j * 8 + d] = t[d] * 0.0625f;
        }
    }
    int e0 = offs[i], e1 = offs[i + 1];
    float m = -1e30f, denom = 0.f;
    float acc[32];
#pragma unroll
    for (int j = 0; j < 32; ++j) acc[j] = 0.f;

    for (int base = e0; base < e1; base += 8) {
        int e = base + e8;
        int sidx = csr[(e < e1) ? e : (e1 - 1)];
        const u8* kp = kv8 + (size_t)sidx * 512 + sub * 32;
        uint4 ka = *(const uint4*)kp;
        uint4 kb = *(const uint4*)(kp + 16);
        uint4 va = *(const uint4*)(kp + 256);
        uint4 vb = *(const uint4*)(kp + 272);
        unsigned kw[8] = {ka.x, ka.y, ka.z, ka.w, kb.x, kb.y, kb.z, kb.w};
        float p = 0.f;
#pragma unroll
        for (int j = 0; j < 8; ++j) {
            float t[4]; dec4(kw[j], t);
            p += qf[j * 4] * t[0] + qf[j * 4 + 1] * t[1] + qf[j * 4 + 2] * t[2] + qf[j * 4 + 3] * t[3];
        }
        p += __shfl_xor(p, 1, 64);
        p += __shfl_xor(p, 2, 64);
        p += __shfl_xor(p, 4, 64);
        if (e >= e1) p = -1e30f;
        float pm = p;
        pm = fmaxf(pm, __shfl_xor(pm, 8, 64));
        pm = fmaxf(pm, __shfl_xor(pm, 16, 64));
        pm = fmaxf(pm, __shfl_xor(pm, 32, 64));
        if (pm > m) {
            float sc = __expf(m - pm);
            denom *= sc;
#pragma unroll
            for (int j = 0; j < 32; ++j) acc[j] *= sc;
            m = pm;
        }
        float w = __expf(p - m);
        denom += w;
        unsigned vw[8] = {va.x, va.y, va.z, va.w, vb.x, vb.y, vb.z, vb.w};
#pragma unroll
        for (int j = 0; j < 8; ++j) {
            float t[4]; dec4(vw[j], t);
            acc[j * 4]     += w * t[0];
            acc[j * 4 + 1] += w * t[1];
            acc[j * 4 + 2] += w * t[2];
            acc[j * 4 + 3] += w * t[3];
        }
    }
    denom += __shfl_xor(denom, 8, 64);
    denom += __shfl_xor(denom, 16, 64);
    denom += __shfl_xor(denom, 32, 64);
    float inv = (denom > 0.f) ? 1.f / denom : 0.f;
#pragma unroll
    for (int j = 0; j < 32; ++j) {
        acc[j] += __shfl_xor(acc[j], 8, 64);
        acc[j] += __shfl_xor(acc[j], 16, 64);
        acc[j] += __shfl_xor(acc[j], 32, 64);
    }
    if (e8 == 0) {
        const u16* skp = qkvs + row + 768 + sub * 32;
        float h[32];
#pragma unroll
        for (int j = 0; j < 4; ++j) {
            int4 sv = *(const int4*)(skp + j * 8);
            float t[8]; cvt8(sv, t);
            u16 o[8];
#pragma unroll
            for (int d = 0; d < 8; ++d) {
                float hv = fmaxf(acc[j * 8 + d] * inv + t[d], 0.f);
                h[j * 8 + d] = hv;
                o[d] = f2bf(hv);
            }
            *(int4*)(hb + (size_t)i * 256 + sub * 32 + j * 8) = *(const int4*)o;
        }
        uint4 p0, p1;
        p0.x = pack4(h[0], h[1], h[2], h[3]);   p0.y = pack4(h[4], h[5], h[6], h[7]);
        p0.z = pack4(h[8], h[9], h[10], h[11]); p0.w = pack4(h[12], h[13], h[14], h[15]);
        p1.x = pack4(h[16], h[17], h[18], h[19]); p1.y = pack4(h[20], h[21], h[22], h[23]);
        p1.z = pack4(h[24], h[25], h[26], h[27]); p1.w = pack4(h[28], h[29], h[30], h[31]);
        *(uint4*)(h8 + (size_t)i * 256 + sub * 32) = p0;
        *(uint4*)(h8 + (size_t)i * 256 + sub * 32 + 16) = p1;
    }
}

// ---------------- SAGE mean: one wave per node, 4 edges x 16 lanes x uint4 ----------------
__global__ __launch_bounds__(256) void k_agg(const u8* __restrict__ h8,
                                             const int* __restrict__ csr,
                                             const int* __restrict__ offs,
                                             u16* __restrict__ mean_out, int N) {
    int w = threadIdx.x >> 6, lane = threadIdx.x & 63;
    int i = blockIdx.x * 4 + w;
    if (i >= N) return;
    int g = lane >> 4, sub = lane & 15;
    int e0 = offs[i], e1 = offs[i + 1];
    float acc[16];
#pragma unroll
    for (int d = 0; d < 16; ++d) acc[d] = 0.f;
    int e = e0;
    for (; e + 8 <= e1; e += 8) {
        int s0 = csr[e + g], s1 = csr[e + 4 + g];
        uint4 r0 = *(const uint4*)(h8 + (size_t)s0 * 256 + sub * 16);
        uint4 r1 = *(const uint4*)(h8 + (size_t)s1 * 256 + sub * 16);
        float f0[16], f1[16];
        dec4(r0.x, f0); dec4(r0.y, f0 + 4); dec4(r0.z, f0 + 8); dec4(r0.w, f0 + 12);
        dec4(r1.x, f1); dec4(r1.y, f1 + 4); dec4(r1.z, f1 + 8); dec4(r1.w, f1 + 12);
#pragma unroll
        for (int d = 0; d < 16; ++d) acc[d] += f0[d] + f1[d];
    }
    for (; e + 4 <= e1; e += 4) {
        int s0 = csr[e + g];
        uint4 r0 = *(const uint4*)(h8 + (size_t)s0 * 256 + sub * 16);
        float f0[16];
        dec4(r0.x, f0); dec4(r0.y, f0 + 4); dec4(r0.z, f0 + 8); dec4(r0.w, f0 + 12);
#pragma unroll
        for (int d = 0; d < 16; ++d) acc[d] += f0[d];
    }
    if (e + g < e1) {
        int s0 = csr[e + g];
        uint4 r0 = *(const uint4*)(h8 + (size_t)s0 * 256 + sub * 16);
        float f0[16];
        dec4(r0.x, f0); dec4(r0.y, f0 + 4); dec4(r0.z, f0 + 8); dec4(r0.w, f0 + 12);
#pragma unroll
        for (int d = 0; d < 16; ++d) acc[d] += f0[d];
    }
#pragma unroll
    for (int d = 0; d < 16; ++d) {
        acc[d] += __shfl_xor(acc[d], 16, 64);
        acc[d] += __shfl_xor(acc[d], 32, 64);
    }
    if (g == 0) {
        int dg = e1 - e0; if (dg < 1) dg = 1;
        float inv = 1.f / (float)dg;
        u16 o16[16];
#pragma unroll
        for (int d = 0; d < 16; ++d) o16[d] = f2bf(acc[d] * inv);
        u16* dst = mean_out + (size_t)i * 256 + sub * 16;
        *(int4*)dst = *(const int4*)&o16[0];
        *(int4*)(dst + 8) = *(const int4*)&o16[8];
    }
}

// ---------------- SAGE GEMM (K=512) + BN / gated residual / relu ----------------
__global__ __launch_bounds__(256) void gemm_sage(
    const u16* __restrict__ meanA, const u16* __restrict__ hin,
    const u16* __restrict__ WlT, const u16* __restrict__ WrT,
    const u16* __restrict__ bl, const u16* __restrict__ gamma,
    const u16* __restrict__ beta, const u16* __restrict__ alpha,
    u16* __restrict__ hout, u8* __restrict__ h8out, float* __restrict__ fout, int M) {
    __shared__ __align__(16) u16 lds[12288];
    u16* As = lds;
    u16* Bs = lds + 8192;
    int tid = threadIdx.x, w = tid >> 6, lane = tid & 63;
    int l15 = lane & 15, quad = lane >> 4;
    int lr = lane >> 3, lc = lane & 7;
    int bm0 = blockIdx.x * 128, n0 = blockIdx.y * 64;
    f32x4 acc[2][4];
#pragma unroll
    for (int a = 0; a < 2; ++a)
#pragma unroll
        for (int b = 0; b < 4; ++b) acc[a][b] = (f32x4){0.f, 0.f, 0.f, 0.f};

    for (int k0 = 0; k0 < 512; k0 += 64) {
        const u16* Asrc = (k0 < 256) ? meanA : hin;
        const u16* Bsrc = (k0 < 256) ? WlT : WrT;
        int kc = k0 & 255;
#pragma unroll
        for (int j = 0; j < 4; ++j) {
            int ar = (w * 4 + j) * 8 + lr;
            int grow = bm0 + ar; if (grow >= M) grow = M - 1;
            gl_lds16(Asrc + (size_t)grow * 256 + kc + lc * 8, &As[(w * 4 + j) * 512]);
        }
#pragma unroll
        for (int j = 0; j < 2; ++j) {
            int nr = (w * 2 + j) * 8 + lr;
            gl_lds16(Bsrc + (size_t)(n0 + nr) * 256 + kc + lc * 8, &Bs[(w * 2 + j) * 512]);
        }
        __syncthreads();
#pragma unroll
        for (int s = 0; s < 2; ++s) {
            bf16x8 a[2], b[4];
#pragma unroll
            for (int t = 0; t < 2; ++t)
                a[t] = *(const bf16x8*)&As[(w * 32 + t * 16 + l15) * 64 + s * 32 + quad * 8];
#pragma unroll
            for (int t = 0; t < 4; ++t)
                b[t] = *(const bf16x8*)&Bs[(t * 16 + l15) * 64 + s * 32 + quad * 8];
#pragma unroll
            for (int rt = 0; rt < 2; ++rt)
#pragma unroll
                for (int ct = 0; ct < 4; ++ct)
                    acc[rt][ct] = __builtin_amdgcn_mfma_f32_16x16x32_bf16(a[rt], b[ct], acc[rt][ct], 0, 0, 0);
        }
        __syncthreads();
    }

    float al = 1.f / (1.f + __expf(-bf2f(alpha[0])));
    float alc = 1.f - al;
    u16* oL = lds + w * 2048;
#pragma unroll
    for (int rt = 0; rt < 2; ++rt)
#pragma unroll
        for (int ct = 0; ct < 4; ++ct) {
            int col = n0 + ct * 16 + l15;
            float g  = bf2f(gamma[col]) * BN_SCALE;
            float be = bf2f(beta[col]);
            float bb = bf2f(bl[col]);
#pragma unroll
            for (int r = 0; r < 4; ++r) {
                int grow = bm0 + w * 32 + rt * 16 + quad * 4 + r;
                float z = (acc[rt][ct][r] + bb) * g + be;
                float prev = (grow < M) ? bf2f(hin[(size_t)grow * 256 + col]) : 0.f;
                z = al * z + alc * prev;
                z = fmaxf(z, 0.f);
                oL[(rt * 16 + quad * 4 + r) * 64 + ct * 16 + l15] = f2bf(z);
                if (fout && grow < M) fout[(size_t)grow * 256 + col] = z;
            }
        }
    if (!hout) return;
    __syncthreads();
#pragma unroll
    for (int j = 0; j < 4; ++j) {
        int orow = j * 8 + lr;
        int grow = bm0 + w * 32 + orow;
        if (grow < M) {
            int4 hv = *(const int4*)&oL[orow * 64 + lc * 8];
            *(int4*)&hout[(size_t)grow * 256 + n0 + lc * 8] = hv;
            float f[8]; cvt8(hv, f);
            uint2 o8;
            o8.x = pack4(f[0], f[1], f[2], f[3]);
            o8.y = pack4(f[4], f[5], f[6], f[7]);
            *(uint2*)(h8out + (size_t)grow * 256 + n0 + lc * 8) = o8;
        }
    }
}

extern "C" void kernel_launch(void* const* d_in, const int* in_sizes, int n_in,
                              void* d_out, int out_size, void* d_ws, size_t ws_size,
                              hipStream_t stream) {
    int N = in_sizes[0] / DIM;
    int E = in_sizes[1] / 2;
    int L = in_sizes[10] / (DIM * DIM);

    const u16* xu = (const u16*)d_in[0];
    const long long* e64 = (const long long*)d_in[1];

    const int map9[9] = {0, 3, 5, 7, 9, 11, 13, 14, 15};
    CvtDesc cd;
    cd.cum[0] = 0;
    for (int t = 0; t < 9; ++t) {
        cd.src[t] = d_in[map9[t]];
        cd.cum[t + 1] = cd.cum[t] + in_sizes[map9[t]];
    }
    int total = cd.cum[9];

    char* ws = (char*)d_ws;
    size_t off = 0;
    auto take = [&](size_t bytes) { size_t c = off; off = (off + bytes + 255) & ~255ULL; return c; };

    u16* arena  = (u16*)(ws + take((size_t)total * 2));
    u16* WT     = (u16*)(ws + take((size_t)(4 + 2 * L) * DIM * DIM * 2));
    int* csr    = (int*)(ws + take((size_t)E * 4));
    int* deg    = (int*)(ws + take((size_t)N * 4));
    int* offs   = (int*)(ws + take((size_t)(N + 1) * 4));
    int* cursor = (int*)(ws + take((size_t)N * 4));
    u16* hB0    = (u16*)(ws + take((size_t)N * DIM * 2));
    u8*  kv8    = (u8*)(ws + take((size_t)N * 512));
    u8*  h8     = (u8*)(ws + take((size_t)N * 256));
    u16* qkvsB  = (u16*)(ws + take((size_t)N * 1024 * 2)); // dead after k_attn
    u16* meanB  = qkvsB;                                   // overlay
    u16* hB1    = qkvsB + (size_t)N * DIM;                 // overlay
    (void)ws_size; (void)n_in; (void)out_size;

    const u16* xb    = arena + cd.cum[0];
    const u16* biasF = arena + cd.cum[1];   // bq|bk|bv|bs contiguous
    const u16* blb   = arena + cd.cum[5];
    const u16* gmb   = arena + cd.cum[6];
    const u16* btb   = arena + cd.cum[7];
    const u16* alb   = arena + cd.cum[8];

    k_convert<<<(total + 255) / 256, 256, 0, stream>>>(cd, xu, e64, arena, total, deg, N);

    TDesc td;
    td.base[0] = nullptr; td.base[1] = d_in[10]; td.base[2] = d_in[12]; td.L = L;
    k_transpose<<<(4 + 2 * L) * 16, 256, 0, stream>>>(td, d_in[2], d_in[4], d_in[6], d_in[8],
                                                      xu, e64, WT);

    int eb = (E + 255) / 256;
    k_edges<<<eb, 256, 0, stream>>>((const int*)d_in[1], xu, deg, E);
    k_scan<<<1, 1024, 0, stream>>>(deg, offs, cursor, N, E);
    k_fill<<<eb, 256, 0, stream>>>((const int*)d_in[1], xu, cursor, csr, E);

    int Mb128 = (N + 127) / 128;
    gemm_qkvs<<<dim3(Mb128, 8), 256, 0, stream>>>(xb, WT, biasF, qkvsB, kv8, N);
    k_attn<<<(N + 3) / 4, 256, 0, stream>>>(qkvsB, kv8, csr, offs, hB0, h8, N);

    for (int l = 0; l < L; ++l) {
        const u16* hin = (l & 1) ? hB1 : hB0;
        u16* hout      = (l == L - 1) ? nullptr : ((l & 1) ? hB0 : hB1);
        u8*  h8o       = (l == L - 1) ? nullptr : h8;
        float* fout    = (l == L - 1) ? (float*)d_out : nullptr;
        k_agg<<<(N + 3) / 4, 256, 0, stream>>>(h8, csr, offs, meanB, N);
        gemm_sage<<<dim3(Mb128, 4), 256, 0, stream>>>(
            meanB, hin, WT + (size_t)(4 + l) * DIM * DIM, WT + (size_t)(4 + L + l) * DIM * DIM,
            blb + (size_t)l * DIM, gmb + (size_t)l * DIM, btb + (size_t)l * DIM,
            alb, hout, h8o, fout, N);
    }
}